// Round 14
// baseline (43509.476 us; speedup 1.0000x reference)
//
#include <hip/hip_runtime.h>
#include <math.h>

// Shapes
#define NB   256   // batch N
#define TDIM 87
#define HD   128
#define H3   384
#define NCLS 43

typedef float f32x4 __attribute__((ext_vector_type(4)));
typedef _Float16 f16x8 __attribute__((ext_vector_type(8)));
typedef _Float16 f16x2 __attribute__((ext_vector_type(2)));

__device__ __forceinline__ float sigmoidf_(float x){ return 1.0f/(1.0f + __expf(-x)); }
__device__ __forceinline__ float tanhf_(float x){ return 1.0f - 2.0f/(1.0f + __expf(2.0f*x)); }
__device__ __forceinline__ float lrelu_(float x){ return x > 0.f ? x : 0.01f*x; }

__device__ __forceinline__ f32x4 gload4(const float* p_){
  f32x4 r;
  asm volatile("global_load_dwordx4 %0, %1, off" : "=v"(r) : "v"(p_));
  return r;
}
__device__ __forceinline__ float dot4v(float acc, f32x4 a, f32x4 b){
  acc = fmaf(a[0], b[0], acc); acc = fmaf(a[1], b[1], acc);
  acc = fmaf(a[2], b[2], acc); acc = fmaf(a[3], b[3], acc);
  return acc;
}
// 8 f16 MACs via 4x v_dot2_f32_f16; shufflevector = subregister access (no pack ops)
__device__ __forceinline__ float dot8h(float acc, f16x8 a, f16x8 b){
  acc = __builtin_amdgcn_fdot2(__builtin_shufflevector(a,a,0,1), __builtin_shufflevector(b,b,0,1), acc, false);
  acc = __builtin_amdgcn_fdot2(__builtin_shufflevector(a,a,2,3), __builtin_shufflevector(b,b,2,3), acc, false);
  acc = __builtin_amdgcn_fdot2(__builtin_shufflevector(a,a,4,5), __builtin_shufflevector(b,b,4,5), acc, false);
  acc = __builtin_amdgcn_fdot2(__builtin_shufflevector(a,a,6,7), __builtin_shufflevector(b,b,6,7), acc, false);
  return acc;
}
__device__ __forceinline__ f16x8 cvt8h(const float* p){
  f16x8 r;
  #pragma unroll
  for (int j=0;j<8;j++) r[j] = (_Float16)p[j];
  return r;
}
__device__ __forceinline__ void h8tof(f16x8 a, f32x4& lo, f32x4& hi){
  lo[0]=(float)a[0]; lo[1]=(float)a[1]; lo[2]=(float)a[2]; lo[3]=(float)a[3];
  hi[0]=(float)a[4]; hi[1]=(float)a[5]; hi[2]=(float)a[6]; hi[3]=(float)a[7];
}

// ---------------- conv1 + relu + maxpool ----------------
__global__ __launch_bounds__(256) void k_conv1(const float* __restrict__ tce,
    const float* __restrict__ w1, const float* __restrict__ b1,
    float* __restrict__ pool1){
  const int n = blockIdx.x, oc = blockIdx.y;
  __shared__ float xs[21*52];
  __shared__ float ws[32];
  __shared__ float cv[17*48];
  const int tid = threadIdx.x;
  const int oh = tid/12, owc = (tid%12)*4;
  const bool act = tid < 204;
  const float bias = b1[oc];
  float acc[4];
  #pragma unroll
  for (int j=0;j<4;j++) acc[j] = bias;
  const float* xin  = tce + (size_t)(n*TDIM)*1050;
  const float* wrow = w1  + (size_t)oc*TDIM*25;
  for (int ic=0; ic<TDIM; ++ic){
    for (int j=tid; j<1050; j+=256){ xs[(j/50)*52 + (j%50)] = xin[(size_t)ic*1050 + j]; }
    if (tid < 25) ws[tid] = wrow[ic*25 + tid];
    __syncthreads();
    if (act){
      float wreg[25];
      #pragma unroll
      for (int u=0;u<25;u++) wreg[u] = ws[u];
      #pragma unroll
      for (int r=0;r<5;r++){
        const float4* xr = (const float4*)&xs[(oh+r)*52 + owc];
        float4 v0 = xr[0], v1 = xr[1];
        float xv[8] = {v0.x,v0.y,v0.z,v0.w,v1.x,v1.y,v1.z,v1.w};
        #pragma unroll
        for (int c=0;c<5;c++){
          float w = wreg[r*5+c];
          #pragma unroll
          for (int j=0;j<4;j++) acc[j] = fmaf(w, xv[c+j], acc[j]);
        }
      }
    }
    __syncthreads();
  }
  if (act){
    #pragma unroll
    for (int j=0;j<4;j++){
      int ow = owc + j;
      if (ow < 46) cv[oh*48 + ow] = fmaxf(acc[j], 0.0f);
    }
  }
  __syncthreads();
  if (tid < 176){
    int ph = tid/22, pw = tid%22;
    float m = -1e30f;
    #pragma unroll
    for (int r=0;r<3;r++)
      #pragma unroll
      for (int c=0;c<3;c++)
        m = fmaxf(m, cv[(2*ph+r)*48 + (2*pw+c)]);
    pool1[((size_t)(n*TDIM+oc))*176 + tid] = m;
  }
}

// ---------------- conv2 + relu + maxpool -> cnn (256,87,8) ----------------
__global__ __launch_bounds__(128) void k_conv2(const float* __restrict__ pool1,
    const float* __restrict__ w2, const float* __restrict__ b2,
    float* __restrict__ cnn){
  const int n = blockIdx.x, oc = blockIdx.y;
  __shared__ float xs[176];
  __shared__ float ws[32];
  __shared__ float cv[72];
  const int tid = threadIdx.x;
  float a = b2[oc];
  const int oh = tid/18, ow = tid%18;
  const float* xin = pool1 + (size_t)n*TDIM*176;
  const float* wr  = w2 + (size_t)oc*TDIM*25;
  for (int ic=0; ic<TDIM; ++ic){
    for (int j=tid; j<176; j+=128) xs[j] = xin[(size_t)ic*176 + j];
    if (tid < 25) ws[tid] = wr[ic*25 + tid];
    __syncthreads();
    if (tid < 72){
      #pragma unroll
      for (int r=0;r<5;r++)
        #pragma unroll
        for (int c=0;c<5;c++)
          a = fmaf(ws[r*5+c], xs[(oh+r)*22 + (ow+c)], a);
    }
    __syncthreads();
  }
  if (tid < 72) cv[tid] = fmaxf(a, 0.0f);
  __syncthreads();
  if (tid < 8){
    float m = -1e30f;
    #pragma unroll
    for (int r=0;r<3;r++)
      #pragma unroll
      for (int c=0;c<3;c++)
        m = fmaxf(m, cv[r*18 + (2*tid+c)]);
    cnn[((size_t)(n*TDIM+oc))*8 + tid] = m;
  }
}

// ---------------- utterance bi-GRU ----------------
__global__ __launch_bounds__(768,3) void k_utt(
    const float* __restrict__ te, const float* __restrict__ cnn,
    const float* __restrict__ wih_f, const float* __restrict__ whh_f,
    const float* __restrict__ bih_f, const float* __restrict__ bhh_f,
    const float* __restrict__ wih_b, const float* __restrict__ whh_b,
    const float* __restrict__ bih_b, const float* __restrict__ bhh_b,
    float* __restrict__ Hall){
  const int bx  = blockIdx.x;
  const int dir = bx & 1;
  const int n   = bx >> 1;
  const int tid = threadIdx.x;
  const int o   = tid >> 1, kh = tid & 1;
  const float* wih = dir ? wih_b : wih_f;
  const float* whh = dir ? whh_b : whh_f;
  const float* bih = dir ? bih_b : bih_f;
  const float* bhh = dir ? bhh_b : bhh_f;
  float wh[64], wi[32];
  { const float4* wp = (const float4*)(whh + (size_t)o*128 + kh*64);
    #pragma unroll
    for (int q=0;q<16;q++){ float4 v=wp[q]; wh[4*q]=v.x; wh[4*q+1]=v.y; wh[4*q+2]=v.z; wh[4*q+3]=v.w; } }
  #pragma unroll
  for (int k=0;k<32;k++){ int c = kh*32 + k; wi[k] = (c < 58) ? wih[(size_t)o*58 + c] : 0.f; }
  const float bI = bih[o], bH = bhh[o];
  __shared__ float h[128];
  __shared__ float xb[64];
  __shared__ float s_rz[256];
  __shared__ float gin_s[128];
  __shared__ float ghn_s[128];
  if (tid < 128) h[tid] = 0.f;
  if (tid < 64)  xb[tid] = 0.f;
  __syncthreads();
  for (int t=0;t<TDIM;++t){
    const int ttt = dir ? (TDIM-1-t) : t;
    if (tid < 50)      xb[tid] = te[((size_t)n*TDIM + ttt)*50 + tid];
    else if (tid < 58) xb[tid] = cnn[((size_t)n*TDIM + ttt)*8 + (tid - 50)];
    __syncthreads();
    float a0=0,a1=0,a2=0,a3=0;
    const float4* hp = (const float4*)&h[kh*64];
    #pragma unroll
    for (int q=0;q<16;q++){ float4 hv=hp[q];
      a0=fmaf(wh[4*q],hv.x,a0); a1=fmaf(wh[4*q+1],hv.y,a1);
      a2=fmaf(wh[4*q+2],hv.z,a2); a3=fmaf(wh[4*q+3],hv.w,a3); }
    float ah = (a0+a1)+(a2+a3);
    float c0=0,c1=0,c2=0,c3=0;
    const float4* xp = (const float4*)&xb[kh*32];
    #pragma unroll
    for (int q=0;q<8;q++){ float4 xv=xp[q];
      c0=fmaf(wi[4*q],xv.x,c0); c1=fmaf(wi[4*q+1],xv.y,c1);
      c2=fmaf(wi[4*q+2],xv.z,c2); c3=fmaf(wi[4*q+3],xv.w,c3); }
    float ai = (c0+c1)+(c2+c3);
    ah += __shfl_xor(ah, 1);
    ai += __shfl_xor(ai, 1);
    if (kh == 0){
      if (o < 256) s_rz[o] = ah + ai + bI + bH;
      else { gin_s[o-256] = ai + bI; ghn_s[o-256] = ah + bH; }
    }
    __syncthreads();
    if (tid < 128){
      float r  = sigmoidf_(s_rz[tid]);
      float z  = sigmoidf_(s_rz[128+tid]);
      float nn = tanhf_(gin_s[tid] + r*ghn_s[tid]);
      h[tid] = (1.f - z)*nn + z*h[tid];
    }
    __syncthreads();
  }
  if (tid < 128) Hall[(size_t)n*256 + dir*128 + tid] = h[tid];
}

// ---------------- prep ----------------
__global__ __launch_bounds__(256) void k_prep(const float* __restrict__ Hall,
    const float* __restrict__ ctx_w1, const float* __restrict__ proj_w,
    float* __restrict__ a_all, float* __restrict__ s_all){
  const int i = blockIdx.x; const int tid = threadIdx.x;
  __shared__ float hr[256];
  __shared__ float red[2];
  hr[tid] = Hall[(size_t)i*256 + tid];
  __syncthreads();
  if (tid < 128){
    const float4* w  = (const float4*)(ctx_w1 + (size_t)tid*256);
    const float4* hp = (const float4*)hr;
    float a0=0,a1=0,a2=0,a3=0;
    #pragma unroll 8
    for (int q=0;q<64;q++){ float4 wv=w[q], hv=hp[q];
      a0=fmaf(wv.x,hv.x,a0); a1=fmaf(wv.y,hv.y,a1); a2=fmaf(wv.z,hv.z,a2); a3=fmaf(wv.w,hv.w,a3); }
    a_all[(size_t)i*128 + tid] = (a0+a1)+(a2+a3);
  } else {
    const int k = tid - 128;
    float p = hr[k]*proj_w[k] + hr[k+128]*proj_w[k+128];
    #pragma unroll
    for (int off=32; off; off>>=1) p += __shfl_xor(p, off);
    if ((tid & 63) == 0) red[(tid-128)>>6] = p;
  }
  __syncthreads();
  if (tid == 0) s_all[i] = red[0] + red[1];
}

// ---------------- ctx scan v14: 2 blocks x 1024 thr; both d-chains in one block (wave TLP) ----------------
// v13 diagnosis: per-cell 1316 cyc >> 480-cyc issue -> latency/sync-bound at 2 waves/SIMD.
// v14: F block hosts chains d=0,1 in tids [0,512),[512,1024) -> 4 waves/SIMD; the second
// chain's issue fills the first's latency shadow (TRUE TLP, unlike v12's in-thread pairing).
// Per-chain structure identical to v13 (f16 weights 48 VGPR pinned, f16 h, fdot2, 1 barrier).
__global__ __launch_bounds__(1024,1) void k_ctx(
    const float* __restrict__ cg_wih_f, const float* __restrict__ cg_whh_f,
    const float* __restrict__ cg_bih_f, const float* __restrict__ cg_bhh_f,
    const float* __restrict__ cg_wih_b, const float* __restrict__ cg_whh_b,
    const float* __restrict__ cg_bih_b, const float* __restrict__ cg_bhh_b,
    const float* __restrict__ ctx_w2, const float* __restrict__ ctx_b2,
    const float* __restrict__ ctx_w3, const float* __restrict__ proj_b,
    const float* __restrict__ gx0,
    const float* __restrict__ a_all, const float* __restrict__ s_all,
    float* __restrict__ one_d_g, int* __restrict__ flags,
    float* __restrict__ feats){
  const bool isF = (blockIdx.x == 0);
  const int tid = threadIdx.x;
  const int ch  = tid >> 9;          // chain d = 0 or 1
  const int lt  = tid & 511;         // local tid within chain
  const int p   = lt >> 2;           // output row [0,128)
  const int kq  = lt & 3;            // K-quarter: 32 values
  const float* whh = isF ? cg_whh_f : cg_whh_b;
  const float* wih = isF ? cg_wih_f : cg_wih_b;
  const float* bih = isF ? cg_bih_f : cg_bih_b;
  const float* bhh = isF ? cg_bhh_f : cg_bhh_b;

  // ---- stationary weights: fp16, 12 f16x8 = 48 VGPR, keep-alive pinned (identical per chain)
  const float* wrb = whh + (size_t)(      p)*128 + kq*32;
  const float* wzb = whh + (size_t)(128 + p)*128 + kq*32;
  const float* wnb = whh + (size_t)(256 + p)*128 + kq*32;
  f16x8 wr0=cvt8h(wrb), wr1=cvt8h(wrb+8), wr2=cvt8h(wrb+16), wr3=cvt8h(wrb+24);
  f16x8 wz0=cvt8h(wzb), wz1=cvt8h(wzb+8), wz2=cvt8h(wzb+16), wz3=cvt8h(wzb+24);
  f16x8 wn0=cvt8h(wnb), wn1=cvt8h(wnb+8), wn2=cvt8h(wnb+16), wn3=cvt8h(wnb+24);
  asm volatile("" : "+v"(wr0), "+v"(wr1), "+v"(wr2), "+v"(wr3),
                    "+v"(wz0), "+v"(wz1), "+v"(wz2), "+v"(wz3),
                    "+v"(wn0), "+v"(wn1), "+v"(wn2), "+v"(wn3));

  // ---- tail scalars (by row p, used in kq==0 lanes)
  float wir = wih[p],      wiz = wih[128+p], win = wih[256+p];
  float br_ = bih[p]      + bhh[p];
  float bz_ = bih[128+p]  + bhh[128+p];
  float bn_ = bih[256+p];
  float bhn_ = bhh[256+p];
  float pb = proj_b[0];
  asm volatile("" : "+v"(wir), "+v"(wiz), "+v"(win), "+v"(br_), "+v"(bz_),
                    "+v"(bn_), "+v"(bhn_), "+v"(pb));

  __shared__ _Float16 hl16[2][2][160];  // [chain][buf][4 chunks of 32 halfs, stride 40]
  __shared__ float one_d_s[2][128];
  __shared__ float T_s[2][160];
  __shared__ float S_s[2][128];
  __shared__ float red_s[2][2];

  const float* gsrc = gx0 + (size_t)((isF ? 0 : 2) + ch)*128;
  float hm = gsrc[p];                   // fp32 running state (kq==0 lanes)
  if (lt < 128) hl16[ch][0][((lt>>5)*40) + (lt&31)] = (_Float16)gsrc[lt];
  __syncthreads();

  const int chp  = ((p>>5)*40) + (p&31);
  const int kb16 = kq*40;

  for (int i=0;i<NB;++i){
    if (isF){
      // ---- attention (both chains run it on their own lt-halves)
      const float* w2r = ctx_w2 + (size_t)p*128 + kq*32;
      const float* w3r = ctx_w3 + (size_t)p*128 + kq*32;
      f32x4 u0=gload4(w2r),    u1=gload4(w2r+4),  u2=gload4(w2r+8),  u3=gload4(w2r+12);
      f32x4 u4=gload4(w2r+16), u5=gload4(w2r+20), u6=gload4(w2r+24), u7=gload4(w2r+28);
      f32x4 v0=gload4(w3r),    v1=gload4(w3r+4),  v2=gload4(w3r+8),  v3=gload4(w3r+12);
      f32x4 v4=gload4(w3r+16), v5=gload4(w3r+20), v6=gload4(w3r+24), v7=gload4(w3r+28);
      asm volatile("s_waitcnt vmcnt(0)" ::: "memory");
      __builtin_amdgcn_sched_barrier(0);
      {
        const f16x8* hp0 = (const f16x8*)&hl16[ch][0][kb16];
        f16x8 a0=hp0[0], a1=hp0[1], a2=hp0[2], a3=hp0[3];
        f32x4 g0,g1,g2,g3,g4,g5,g6,g7;
        h8tof(a0,g0,g1); h8tof(a1,g2,g3); h8tof(a2,g4,g5); h8tof(a3,g6,g7);
        float s=0;
        s=dot4v(s,u0,g0); s=dot4v(s,u1,g1); s=dot4v(s,u2,g2); s=dot4v(s,u3,g3);
        s=dot4v(s,u4,g4); s=dot4v(s,u5,g5); s=dot4v(s,u6,g6); s=dot4v(s,u7,g7);
        s += __shfl_xor(s,1); s += __shfl_xor(s,2);
        if (kq == 0) T_s[ch][((p>>4)*20)+(p&15)] = tanhf_(a_all[(size_t)i*128 + p] + s + ctx_b2[p]);
      }
      __syncthreads();
      {
        const f32x4* tA = (const f32x4*)&T_s[ch][kq*40];
        const f32x4* tB = (const f32x4*)&T_s[ch][kq*40+20];
        f32x4 t0=tA[0],t1=tA[1],t2=tA[2],t3=tA[3];
        f32x4 t4=tB[0],t5=tB[1],t6=tB[2],t7=tB[3];
        float s=0;
        s=dot4v(s,v0,t0); s=dot4v(s,v1,t1); s=dot4v(s,v2,t2); s=dot4v(s,v3,t3);
        s=dot4v(s,v4,t4); s=dot4v(s,v5,t5); s=dot4v(s,v6,t6); s=dot4v(s,v7,t7);
        s += __shfl_xor(s,1); s += __shfl_xor(s,2);
        if (kq == 0) S_s[ch][p] = s;
      }
      __syncthreads();
      if (lt < 64){
        float m = fmaxf(S_s[ch][lt], S_s[ch][lt+64]);
        #pragma unroll
        for (int off=32; off; off>>=1) m = fmaxf(m, __shfl_xor(m, off));
        if (lt == 0) red_s[ch][0] = m;
      }
      __syncthreads();
      if (lt < 128) S_s[ch][lt] = __expf(S_s[ch][lt] - red_s[ch][0]);
      __syncthreads();
      if (lt < 64){
        float s = S_s[ch][lt] + S_s[ch][lt+64];
        #pragma unroll
        for (int off=32; off; off>>=1) s += __shfl_xor(s, off);
        if (lt == 0) red_s[ch][1] = s;
      }
      __syncthreads();
      if (lt < 128){
        float v = (S_s[ch][lt] / red_s[ch][1]) * s_all[i] + pb;
        one_d_s[ch][lt] = v;
        __hip_atomic_store(&one_d_g[((size_t)ch*NB + i)*128 + lt], v,
                           __ATOMIC_RELAXED, __HIP_MEMORY_SCOPE_AGENT);
      }
      __syncthreads();
      if (tid == 0){
        __threadfence();
        __hip_atomic_store(&flags[0], i+1, __ATOMIC_RELEASE, __HIP_MEMORY_SCOPE_AGENT);
      }
    } else {
      if (tid == 0){
        while (__hip_atomic_load(&flags[0], __ATOMIC_ACQUIRE, __HIP_MEMORY_SCOPE_AGENT) < i+1){
          __builtin_amdgcn_s_sleep(8);
        }
      }
      __syncthreads();
      if (lt < 128)
        one_d_s[ch][lt] = __hip_atomic_load(&one_d_g[((size_t)ch*NB + i)*128 + lt],
                                            __ATOMIC_RELAXED, __HIP_MEMORY_SCOPE_AGENT);
      __syncthreads();
    }
    // ---- inner GRU: 128 cells, ONE barrier each; two chains in separate wave-groups
    for (int tc=0; tc<128; ++tc){
      const _Float16* hcur = hl16[ch][tc & 1];
      _Float16*       hnxt = hl16[ch][(tc & 1) ^ 1];
      const f16x8* hp = (const f16x8*)&hcur[kb16];
      f16x8 h0=hp[0], h1=hp[1], h2=hp[2], h3=hp[3];
      float ar=0, az=0, an=0;
      ar=dot8h(ar,wr0,h0); ar=dot8h(ar,wr1,h1); ar=dot8h(ar,wr2,h2); ar=dot8h(ar,wr3,h3);
      az=dot8h(az,wz0,h0); az=dot8h(az,wz1,h1); az=dot8h(az,wz2,h2); az=dot8h(az,wz3,h3);
      an=dot8h(an,wn0,h0); an=dot8h(an,wn1,h1); an=dot8h(an,wn2,h2); an=dot8h(an,wn3,h3);
      ar += __shfl_xor(ar,1); ar += __shfl_xor(ar,2);
      az += __shfl_xor(az,1); az += __shfl_xor(az,2);
      an += __shfl_xor(an,1); an += __shfl_xor(an,2);
      if (kq == 0){
        float x = one_d_s[ch][isF ? tc : 127-tc];
        float r  = sigmoidf_(fmaf(x, wir, br_) + ar);
        float z  = sigmoidf_(fmaf(x, wiz, bz_) + az);
        float nn = tanhf_(fmaf(x, win, bn_) + r*(an + bhn_));
        hm = (1.f - z)*nn + z*hm;
        hnxt[chp] = (_Float16)hm;
      }
      __syncthreads();
    }
    if (kq == 0){
      const int off = isF ? ch*128 : 256 + ch*128;
      feats[(size_t)i*512 + off + p] = hm;
    }
    __syncthreads();
  }
}

// ---------------- classifier ----------------
__global__ __launch_bounds__(256) void k_cls(const float* __restrict__ feats,
    const float* __restrict__ w1, const float* __restrict__ b1,
    const float* __restrict__ w2, const float* __restrict__ b2,
    const float* __restrict__ w3, const float* __restrict__ b3,
    float* __restrict__ out){
  const int n = blockIdx.x; const int tid = threadIdx.x;
  __shared__ float fr[512];
  __shared__ float h1s[256];
  __shared__ float h2s[128];
  fr[tid]       = feats[(size_t)n*512 + tid];
  fr[tid+256]   = feats[(size_t)n*512 + 256 + tid];
  __syncthreads();
  {
    const float4* w  = (const float4*)(w1 + (size_t)tid*512);
    const float4* fp = (const float4*)fr;
    float a0=0,a1=0,a2=0,a3=0;
    #pragma unroll 8
    for (int q=0;q<128;q++){ float4 wv=w[q], fv=fp[q];
      a0=fmaf(wv.x,fv.x,a0); a1=fmaf(wv.y,fv.y,a1); a2=fmaf(wv.z,fv.z,a2); a3=fmaf(wv.w,fv.w,a3); }
    h1s[tid] = lrelu_(b1[tid] + (a0+a1)+(a2+a3));
  }
  __syncthreads();
  if (tid < 128){
    const float4* w  = (const float4*)(w2 + (size_t)tid*256);
    const float4* fp = (const float4*)h1s;
    float a0=0,a1=0,a2=0,a3=0;
    #pragma unroll 8
    for (int q=0;q<64;q++){ float4 wv=w[q], fv=fp[q];
      a0=fmaf(wv.x,fv.x,a0); a1=fmaf(wv.y,fv.y,a1); a2=fmaf(wv.z,fv.z,a2); a3=fmaf(wv.w,fv.w,a3); }
    h2s[tid] = lrelu_(b2[tid] + (a0+a1)+(a2+a3));
  }
  __syncthreads();
  if (tid < NCLS){
    const float4* w  = (const float4*)(w3 + (size_t)tid*128);
    const float4* fp = (const float4*)h2s;
    float a0=0,a1=0,a2=0,a3=0;
    #pragma unroll 8
    for (int q=0;q<32;q++){ float4 wv=w[q], fv=fp[q];
      a0=fmaf(wv.x,fv.x,a0); a1=fmaf(wv.y,fv.y,a1); a2=fmaf(wv.z,fv.z,a2); a3=fmaf(wv.w,fv.w,a3); }
    out[(size_t)n*NCLS + tid] = b3[tid] + (a0+a1)+(a2+a3);
  }
}

// ---------------- workspace layout (bytes) ----------------
#define OFF_FLAGS  0u
#define OFF_SALL   512u
#define OFF_AALL   2048u
#define OFF_ONED   133632u
#define OFF_HALL   395776u
#define OFF_FEATS  657920u
#define OFF_CNN    1182208u
#define OFF_POOL1  1894912u

extern "C" void kernel_launch(void* const* d_in, const int* in_sizes, int n_in,
                              void* d_out, int out_size, void* d_ws, size_t ws_size,
                              hipStream_t stream){
  const float* te   = (const float*)d_in[0];
  const float* tce  = (const float*)d_in[1];
  const float* c1w  = (const float*)d_in[2];
  const float* c1b  = (const float*)d_in[3];
  const float* c2w  = (const float*)d_in[4];
  const float* c2b  = (const float*)d_in[5];
  const float* uwif = (const float*)d_in[6];
  const float* uwhf = (const float*)d_in[7];
  const float* ubif = (const float*)d_in[8];
  const float* ubhf = (const float*)d_in[9];
  const float* uwib = (const float*)d_in[10];
  const float* uwhb = (const float*)d_in[11];
  const float* ubib = (const float*)d_in[12];
  const float* ubhb = (const float*)d_in[13];
  const float* cw1  = (const float*)d_in[14];
  const float* cw2  = (const float*)d_in[15];
  const float* cb2  = (const float*)d_in[16];
  const float* cw3  = (const float*)d_in[17];
  const float* pw   = (const float*)d_in[18];
  const float* pbb  = (const float*)d_in[19];
  const float* gx0  = (const float*)d_in[20];
  const float* gwif = (const float*)d_in[21];
  const float* gwhf = (const float*)d_in[22];
  const float* gbif = (const float*)d_in[23];
  const float* gbhf = (const float*)d_in[24];
  const float* gwib = (const float*)d_in[25];
  const float* gwhb = (const float*)d_in[26];
  const float* gbib = (const float*)d_in[27];
  const float* gbhb = (const float*)d_in[28];
  const float* clw1 = (const float*)d_in[29];
  const float* clb1 = (const float*)d_in[30];
  const float* clw2 = (const float*)d_in[31];
  const float* clb2 = (const float*)d_in[32];
  const float* clw3 = (const float*)d_in[33];
  const float* clb3 = (const float*)d_in[34];
  float* out = (float*)d_out;
  char* ws = (char*)d_ws;
  int*   flags = (int*)  (ws + OFF_FLAGS);
  float* s_all = (float*)(ws + OFF_SALL);
  float* a_all = (float*)(ws + OFF_AALL);
  float* one_d = (float*)(ws + OFF_ONED);
  float* Hall  = (float*)(ws + OFF_HALL);
  float* feats = (float*)(ws + OFF_FEATS);
  float* cnn   = (float*)(ws + OFF_CNN);
  float* pool1 = (float*)(ws + OFF_POOL1);

  hipMemsetAsync(flags, 0, 64, stream);
  k_conv1<<<dim3(NB, TDIM), 256, 0, stream>>>(tce, c1w, c1b, pool1);
  k_conv2<<<dim3(NB, TDIM), 128, 0, stream>>>(pool1, c2w, c2b, cnn);
  k_utt<<<512, 768, 0, stream>>>(te, cnn, uwif, uwhf, ubif, ubhf,
                                 uwib, uwhb, ubib, ubhb, Hall);
  k_prep<<<NB, 256, 0, stream>>>(Hall, cw1, pw, a_all, s_all);
  k_ctx<<<2, 1024, 0, stream>>>(gwif, gwhf, gbif, gbhf, gwib, gwhb, gbib, gbhb,
                                cw2, cb2, cw3, pbb, gx0, a_all, s_all,
                                one_d, flags, feats);
  k_cls<<<NB, 256, 0, stream>>>(feats, clw1, clb1, clw2, clb2, clw3, clb3, out);
}

// Round 16
// 22513.448 us; speedup vs baseline: 1.9326x; 1.9326x over previous
//
#include <hip/hip_runtime.h>
#include <math.h>

// Shapes
#define NB   256   // batch N
#define TDIM 87
#define HD   128
#define H3   384
#define NCLS 43

typedef float f32x4 __attribute__((ext_vector_type(4)));
typedef _Float16 f16x8 __attribute__((ext_vector_type(8)));
typedef _Float16 f16x2 __attribute__((ext_vector_type(2)));

__device__ __forceinline__ float sigmoidf_(float x){ return 1.0f/(1.0f + __expf(-x)); }
__device__ __forceinline__ float tanhf_(float x){ return 1.0f - 2.0f/(1.0f + __expf(2.0f*x)); }
__device__ __forceinline__ float lrelu_(float x){ return x > 0.f ? x : 0.01f*x; }

__device__ __forceinline__ f32x4 gload4(const float* p_){
  f32x4 r;
  asm volatile("global_load_dwordx4 %0, %1, off" : "=v"(r) : "v"(p_));
  return r;
}
__device__ __forceinline__ float dot4v(float acc, f32x4 a, f32x4 b){
  acc = fmaf(a[0], b[0], acc); acc = fmaf(a[1], b[1], acc);
  acc = fmaf(a[2], b[2], acc); acc = fmaf(a[3], b[3], acc);
  return acc;
}
// 8 f16 MACs via 4x v_dot2_f32_f16; shufflevector = subregister access (no pack ops)
__device__ __forceinline__ float dot8h(float acc, f16x8 a, f16x8 b){
  acc = __builtin_amdgcn_fdot2(__builtin_shufflevector(a,a,0,1), __builtin_shufflevector(b,b,0,1), acc, false);
  acc = __builtin_amdgcn_fdot2(__builtin_shufflevector(a,a,2,3), __builtin_shufflevector(b,b,2,3), acc, false);
  acc = __builtin_amdgcn_fdot2(__builtin_shufflevector(a,a,4,5), __builtin_shufflevector(b,b,4,5), acc, false);
  acc = __builtin_amdgcn_fdot2(__builtin_shufflevector(a,a,6,7), __builtin_shufflevector(b,b,6,7), acc, false);
  return acc;
}
__device__ __forceinline__ f16x8 cvt8h(const float* p){
  f16x8 r;
  #pragma unroll
  for (int j=0;j<8;j++) r[j] = (_Float16)p[j];
  return r;
}
__device__ __forceinline__ void h8tof(f16x8 a, f32x4& lo, f32x4& hi){
  lo[0]=(float)a[0]; lo[1]=(float)a[1]; lo[2]=(float)a[2]; lo[3]=(float)a[3];
  hi[0]=(float)a[4]; hi[1]=(float)a[5]; hi[2]=(float)a[6]; hi[3]=(float)a[7];
}

// ---------------- conv1 + relu + maxpool ----------------
// grid = dim3(TDIM, NB): consecutive blocks share one sample's input slice -> L2 locality.
__global__ __launch_bounds__(256) void k_conv1(const float* __restrict__ tce,
    const float* __restrict__ w1, const float* __restrict__ b1,
    float* __restrict__ pool1){
  const int oc = blockIdx.x, n = blockIdx.y;
  __shared__ float xs[21*52];
  __shared__ float ws[32];
  __shared__ float cv[17*48];
  const int tid = threadIdx.x;
  const int oh = tid/12, owc = (tid%12)*4;
  const bool act = tid < 204;
  const float bias = b1[oc];
  float acc[4];
  #pragma unroll
  for (int j=0;j<4;j++) acc[j] = bias;
  const float* xin  = tce + (size_t)(n*TDIM)*1050;
  const float* wrow = w1  + (size_t)oc*TDIM*25;
  for (int ic=0; ic<TDIM; ++ic){
    for (int j=tid; j<1050; j+=256){ xs[(j/50)*52 + (j%50)] = xin[(size_t)ic*1050 + j]; }
    if (tid < 25) ws[tid] = wrow[ic*25 + tid];
    __syncthreads();
    if (act){
      float wreg[25];
      #pragma unroll
      for (int u=0;u<25;u++) wreg[u] = ws[u];
      #pragma unroll
      for (int r=0;r<5;r++){
        const float4* xr = (const float4*)&xs[(oh+r)*52 + owc];
        float4 v0 = xr[0], v1 = xr[1];
        float xv[8] = {v0.x,v0.y,v0.z,v0.w,v1.x,v1.y,v1.z,v1.w};
        #pragma unroll
        for (int c=0;c<5;c++){
          float w = wreg[r*5+c];
          #pragma unroll
          for (int j=0;j<4;j++) acc[j] = fmaf(w, xv[c+j], acc[j]);
        }
      }
    }
    __syncthreads();
  }
  if (act){
    #pragma unroll
    for (int j=0;j<4;j++){
      int ow = owc + j;
      if (ow < 46) cv[oh*48 + ow] = fmaxf(acc[j], 0.0f);
    }
  }
  __syncthreads();
  if (tid < 176){
    int ph = tid/22, pw = tid%22;
    float m = -1e30f;
    #pragma unroll
    for (int r=0;r<3;r++)
      #pragma unroll
      for (int c=0;c<3;c++)
        m = fmaxf(m, cv[(2*ph+r)*48 + (2*pw+c)]);
    pool1[((size_t)(n*TDIM+oc))*176 + tid] = m;
  }
}

// ---------------- conv2 + relu + maxpool -> cnn (256,87,8) ----------------
__global__ __launch_bounds__(128) void k_conv2(const float* __restrict__ pool1,
    const float* __restrict__ w2, const float* __restrict__ b2,
    float* __restrict__ cnn){
  const int oc = blockIdx.x, n = blockIdx.y;
  __shared__ float xs[176];
  __shared__ float ws[32];
  __shared__ float cv[72];
  const int tid = threadIdx.x;
  float a = b2[oc];
  const int oh = tid/18, ow = tid%18;
  const float* xin = pool1 + (size_t)n*TDIM*176;
  const float* wr  = w2 + (size_t)oc*TDIM*25;
  for (int ic=0; ic<TDIM; ++ic){
    for (int j=tid; j<176; j+=128) xs[j] = xin[(size_t)ic*176 + j];
    if (tid < 25) ws[tid] = wr[ic*25 + tid];
    __syncthreads();
    if (tid < 72){
      #pragma unroll
      for (int r=0;r<5;r++)
        #pragma unroll
        for (int c=0;c<5;c++)
          a = fmaf(ws[r*5+c], xs[(oh+r)*22 + (ow+c)], a);
    }
    __syncthreads();
  }
  if (tid < 72) cv[tid] = fmaxf(a, 0.0f);
  __syncthreads();
  if (tid < 8){
    float m = -1e30f;
    #pragma unroll
    for (int r=0;r<3;r++)
      #pragma unroll
      for (int c=0;c<3;c++)
        m = fmaxf(m, cv[r*18 + (2*tid+c)]);
    cnn[((size_t)(n*TDIM+oc))*8 + tid] = m;
  }
}

// ---------------- utterance bi-GRU ----------------
__global__ __launch_bounds__(768,3) void k_utt(
    const float* __restrict__ te, const float* __restrict__ cnn,
    const float* __restrict__ wih_f, const float* __restrict__ whh_f,
    const float* __restrict__ bih_f, const float* __restrict__ bhh_f,
    const float* __restrict__ wih_b, const float* __restrict__ whh_b,
    const float* __restrict__ bih_b, const float* __restrict__ bhh_b,
    float* __restrict__ Hall){
  const int bx  = blockIdx.x;
  const int dir = bx & 1;
  const int n   = bx >> 1;
  const int tid = threadIdx.x;
  const int o   = tid >> 1, kh = tid & 1;
  const float* wih = dir ? wih_b : wih_f;
  const float* whh = dir ? whh_b : whh_f;
  const float* bih = dir ? bih_b : bih_f;
  const float* bhh = dir ? bhh_b : bhh_f;
  float wh[64], wi[32];
  { const float4* wp = (const float4*)(whh + (size_t)o*128 + kh*64);
    #pragma unroll
    for (int q=0;q<16;q++){ float4 v=wp[q]; wh[4*q]=v.x; wh[4*q+1]=v.y; wh[4*q+2]=v.z; wh[4*q+3]=v.w; } }
  #pragma unroll
  for (int k=0;k<32;k++){ int c = kh*32 + k; wi[k] = (c < 58) ? wih[(size_t)o*58 + c] : 0.f; }
  const float bI = bih[o], bH = bhh[o];
  __shared__ float h[128];
  __shared__ float xb[64];
  __shared__ float s_rz[256];
  __shared__ float gin_s[128];
  __shared__ float ghn_s[128];
  if (tid < 128) h[tid] = 0.f;
  if (tid < 64)  xb[tid] = 0.f;
  __syncthreads();
  for (int t=0;t<TDIM;++t){
    const int ttt = dir ? (TDIM-1-t) : t;
    if (tid < 50)      xb[tid] = te[((size_t)n*TDIM + ttt)*50 + tid];
    else if (tid < 58) xb[tid] = cnn[((size_t)n*TDIM + ttt)*8 + (tid - 50)];
    __syncthreads();
    float a0=0,a1=0,a2=0,a3=0;
    const float4* hp = (const float4*)&h[kh*64];
    #pragma unroll
    for (int q=0;q<16;q++){ float4 hv=hp[q];
      a0=fmaf(wh[4*q],hv.x,a0); a1=fmaf(wh[4*q+1],hv.y,a1);
      a2=fmaf(wh[4*q+2],hv.z,a2); a3=fmaf(wh[4*q+3],hv.w,a3); }
    float ah = (a0+a1)+(a2+a3);
    float c0=0,c1=0,c2=0,c3=0;
    const float4* xp = (const float4*)&xb[kh*32];
    #pragma unroll
    for (int q=0;q<8;q++){ float4 xv=xp[q];
      c0=fmaf(wi[4*q],xv.x,c0); c1=fmaf(wi[4*q+1],xv.y,c1);
      c2=fmaf(wi[4*q+2],xv.z,c2); c3=fmaf(wi[4*q+3],xv.w,c3); }
    float ai = (c0+c1)+(c2+c3);
    ah += __shfl_xor(ah, 1);
    ai += __shfl_xor(ai, 1);
    if (kh == 0){
      if (o < 256) s_rz[o] = ah + ai + bI + bH;
      else { gin_s[o-256] = ai + bI; ghn_s[o-256] = ah + bH; }
    }
    __syncthreads();
    if (tid < 128){
      float r  = sigmoidf_(s_rz[tid]);
      float z  = sigmoidf_(s_rz[128+tid]);
      float nn = tanhf_(gin_s[tid] + r*ghn_s[tid]);
      h[tid] = (1.f - z)*nn + z*h[tid];
    }
    __syncthreads();
  }
  if (tid < 128) Hall[(size_t)n*256 + dir*128 + tid] = h[tid];
}

// ---------------- prep ----------------
__global__ __launch_bounds__(256) void k_prep(const float* __restrict__ Hall,
    const float* __restrict__ ctx_w1, const float* __restrict__ proj_w,
    float* __restrict__ a_all, float* __restrict__ s_all){
  const int i = blockIdx.x; const int tid = threadIdx.x;
  __shared__ float hr[256];
  __shared__ float red[2];
  hr[tid] = Hall[(size_t)i*256 + tid];
  __syncthreads();
  if (tid < 128){
    const float4* w  = (const float4*)(ctx_w1 + (size_t)tid*256);
    const float4* hp = (const float4*)hr;
    float a0=0,a1=0,a2=0,a3=0;
    #pragma unroll 8
    for (int q=0;q<64;q++){ float4 wv=w[q], hv=hp[q];
      a0=fmaf(wv.x,hv.x,a0); a1=fmaf(wv.y,hv.y,a1); a2=fmaf(wv.z,hv.z,a2); a3=fmaf(wv.w,hv.w,a3); }
    a_all[(size_t)i*128 + tid] = (a0+a1)+(a2+a3);
  } else {
    const int k = tid - 128;
    float p = hr[k]*proj_w[k] + hr[k+128]*proj_w[k+128];
    #pragma unroll
    for (int off=32; off; off>>=1) p += __shfl_xor(p, off);
    if ((tid & 63) == 0) red[(tid-128)>>6] = p;
  }
  __syncthreads();
  if (tid == 0) s_all[i] = red[0] + red[1];
}

// ---------------- ctx scan v13 (final): 4 blocks / 512 thr / 8 waves, f16 weights+h, fdot2 ----------------
// Best measured: 17.96 ms (1316 cyc/cell). Residual = barrier-synced serial dependency chain;
// all TLP restructurings falsified (v12 in-thread: serializes; v14: spills at (1024,1);
// v15: miscompiles at (1024,4) 128-VGPR exact-fit with tied-asm operands).
__global__ __launch_bounds__(512,2) void k_ctx(
    const float* __restrict__ cg_wih_f, const float* __restrict__ cg_whh_f,
    const float* __restrict__ cg_bih_f, const float* __restrict__ cg_bhh_f,
    const float* __restrict__ cg_wih_b, const float* __restrict__ cg_whh_b,
    const float* __restrict__ cg_bih_b, const float* __restrict__ cg_bhh_b,
    const float* __restrict__ ctx_w2, const float* __restrict__ ctx_b2,
    const float* __restrict__ ctx_w3, const float* __restrict__ proj_b,
    const float* __restrict__ gx0,
    const float* __restrict__ a_all, const float* __restrict__ s_all,
    float* __restrict__ one_d_g, int* __restrict__ flags,
    float* __restrict__ feats){
  const int blk = blockIdx.x;
  const bool isF = blk < 2;
  const int d   = blk & 1;
  const int tid = threadIdx.x;
  const int p   = tid >> 2;      // output row [0,128)
  const int kq  = tid & 3;       // K-quarter: 32 values
  const float* whh = isF ? cg_whh_f : cg_whh_b;
  const float* wih = isF ? cg_wih_f : cg_wih_b;
  const float* bih = isF ? cg_bih_f : cg_bih_b;
  const float* bhh = isF ? cg_bhh_f : cg_bhh_b;

  // ---- stationary weights: fp16, 12 f16x8 = 48 VGPR, keep-alive pinned
  const float* wrb = whh + (size_t)(      p)*128 + kq*32;
  const float* wzb = whh + (size_t)(128 + p)*128 + kq*32;
  const float* wnb = whh + (size_t)(256 + p)*128 + kq*32;
  f16x8 wr0=cvt8h(wrb), wr1=cvt8h(wrb+8), wr2=cvt8h(wrb+16), wr3=cvt8h(wrb+24);
  f16x8 wz0=cvt8h(wzb), wz1=cvt8h(wzb+8), wz2=cvt8h(wzb+16), wz3=cvt8h(wzb+24);
  f16x8 wn0=cvt8h(wnb), wn1=cvt8h(wnb+8), wn2=cvt8h(wnb+16), wn3=cvt8h(wnb+24);
  asm volatile("" : "+v"(wr0), "+v"(wr1), "+v"(wr2), "+v"(wr3),
                    "+v"(wz0), "+v"(wz1), "+v"(wz2), "+v"(wz3),
                    "+v"(wn0), "+v"(wn1), "+v"(wn2), "+v"(wn3));

  // ---- tail scalars (by row p, used in kq==0 lanes), keep-alive blocks remat
  float wir = wih[p],      wiz = wih[128+p], win = wih[256+p];
  float br_ = bih[p]      + bhh[p];
  float bz_ = bih[128+p]  + bhh[128+p];
  float bn_ = bih[256+p];
  float bhn_ = bhh[256+p];
  float pb = proj_b[0];
  asm volatile("" : "+v"(wir), "+v"(wiz), "+v"(win), "+v"(br_), "+v"(bz_),
                    "+v"(bn_), "+v"(bhn_), "+v"(pb));

  __shared__ _Float16 hl16[2][160];  // 4 chunks of 32 halfs, stride 40 -> kq bases at banks 0/20/8/28
  __shared__ float one_d_s[128];
  __shared__ float T_s[160];         // fp32, 8 chunks of 16 floats, stride 20
  __shared__ float S_s[128];
  __shared__ float red_s[2];

  const float* gsrc = gx0 + (size_t)((isF ? 0 : 2) + d)*128;
  float hm = gsrc[p];                // fp32 running state (kq==0 lanes)
  if (tid < 128) hl16[0][((tid>>5)*40) + (tid&31)] = (_Float16)gsrc[tid];
  __syncthreads();

  const int chp  = ((p>>5)*40) + (p&31);  // row p's h slot (halfs)
  const int kb16 = kq*40;                 // half-index base of K-slice

  for (int i=0;i<NB;++i){
    if (isF){
      // ---- attention (reads hl16[0] = h after previous outer step)
      const float* w2r = ctx_w2 + (size_t)p*128 + kq*32;
      const float* w3r = ctx_w3 + (size_t)p*128 + kq*32;
      f32x4 u0=gload4(w2r),    u1=gload4(w2r+4),  u2=gload4(w2r+8),  u3=gload4(w2r+12);
      f32x4 u4=gload4(w2r+16), u5=gload4(w2r+20), u6=gload4(w2r+24), u7=gload4(w2r+28);
      f32x4 v0=gload4(w3r),    v1=gload4(w3r+4),  v2=gload4(w3r+8),  v3=gload4(w3r+12);
      f32x4 v4=gload4(w3r+16), v5=gload4(w3r+20), v6=gload4(w3r+24), v7=gload4(w3r+28);
      asm volatile("s_waitcnt vmcnt(0)" ::: "memory");
      __builtin_amdgcn_sched_barrier(0);
      {
        const f16x8* hp0 = (const f16x8*)&hl16[0][kb16];
        f16x8 a0=hp0[0], a1=hp0[1], a2=hp0[2], a3=hp0[3];
        f32x4 g0,g1,g2,g3,g4,g5,g6,g7;
        h8tof(a0,g0,g1); h8tof(a1,g2,g3); h8tof(a2,g4,g5); h8tof(a3,g6,g7);
        float s=0;
        s=dot4v(s,u0,g0); s=dot4v(s,u1,g1); s=dot4v(s,u2,g2); s=dot4v(s,u3,g3);
        s=dot4v(s,u4,g4); s=dot4v(s,u5,g5); s=dot4v(s,u6,g6); s=dot4v(s,u7,g7);
        s += __shfl_xor(s,1); s += __shfl_xor(s,2);
        if (kq == 0) T_s[((p>>4)*20)+(p&15)] = tanhf_(a_all[(size_t)i*128 + p] + s + ctx_b2[p]);
      }
      __syncthreads();
      {
        const f32x4* tA = (const f32x4*)&T_s[kq*40];
        const f32x4* tB = (const f32x4*)&T_s[kq*40+20];
        f32x4 t0=tA[0],t1=tA[1],t2=tA[2],t3=tA[3];
        f32x4 t4=tB[0],t5=tB[1],t6=tB[2],t7=tB[3];
        float s=0;
        s=dot4v(s,v0,t0); s=dot4v(s,v1,t1); s=dot4v(s,v2,t2); s=dot4v(s,v3,t3);
        s=dot4v(s,v4,t4); s=dot4v(s,v5,t5); s=dot4v(s,v6,t6); s=dot4v(s,v7,t7);
        s += __shfl_xor(s,1); s += __shfl_xor(s,2);
        if (kq == 0) S_s[p] = s;
      }
      __syncthreads();
      if (tid < 64){
        float m = fmaxf(S_s[tid], S_s[tid+64]);
        #pragma unroll
        for (int off=32; off; off>>=1) m = fmaxf(m, __shfl_xor(m, off));
        if (tid == 0) red_s[0] = m;
      }
      __syncthreads();
      if (tid < 128) S_s[tid] = __expf(S_s[tid] - red_s[0]);
      __syncthreads();
      if (tid < 64){
        float s = S_s[tid] + S_s[tid+64];
        #pragma unroll
        for (int off=32; off; off>>=1) s += __shfl_xor(s, off);
        if (tid == 0) red_s[1] = s;
      }
      __syncthreads();
      if (tid < 128){
        float v = (S_s[tid] / red_s[1]) * s_all[i] + pb;
        one_d_s[tid] = v;
        __hip_atomic_store(&one_d_g[((size_t)d*NB + i)*128 + tid], v,
                           __ATOMIC_RELAXED, __HIP_MEMORY_SCOPE_AGENT);
      }
      __syncthreads();
      if (tid == 0){
        __threadfence();
        __hip_atomic_store(&flags[d], i+1, __ATOMIC_RELEASE, __HIP_MEMORY_SCOPE_AGENT);
      }
    } else {
      if (tid == 0){
        while (__hip_atomic_load(&flags[d], __ATOMIC_ACQUIRE, __HIP_MEMORY_SCOPE_AGENT) < i+1){
          __builtin_amdgcn_s_sleep(8);
        }
      }
      __syncthreads();
      if (tid < 128)
        one_d_s[tid] = __hip_atomic_load(&one_d_g[((size_t)d*NB + i)*128 + tid],
                                         __ATOMIC_RELAXED, __HIP_MEMORY_SCOPE_AGENT);
      __syncthreads();
    }
    // ---- inner GRU: 128 cells, ONE barrier each, 4x ds_read_b128 + 12x dot8h, divergent tail
    for (int tc=0; tc<128; ++tc){
      const _Float16* hcur = hl16[tc & 1];
      _Float16*       hnxt = hl16[(tc & 1) ^ 1];
      const f16x8* hp = (const f16x8*)&hcur[kb16];
      f16x8 h0=hp[0], h1=hp[1], h2=hp[2], h3=hp[3];
      float ar=0, az=0, an=0;
      ar=dot8h(ar,wr0,h0); ar=dot8h(ar,wr1,h1); ar=dot8h(ar,wr2,h2); ar=dot8h(ar,wr3,h3);
      az=dot8h(az,wz0,h0); az=dot8h(az,wz1,h1); az=dot8h(az,wz2,h2); az=dot8h(az,wz3,h3);
      an=dot8h(an,wn0,h0); an=dot8h(an,wn1,h1); an=dot8h(an,wn2,h2); an=dot8h(an,wn3,h3);
      ar += __shfl_xor(ar,1); ar += __shfl_xor(ar,2);
      az += __shfl_xor(az,1); az += __shfl_xor(az,2);
      an += __shfl_xor(an,1); an += __shfl_xor(an,2);
      if (kq == 0){
        float x = one_d_s[isF ? tc : 127-tc];
        float r  = sigmoidf_(fmaf(x, wir, br_) + ar);
        float z  = sigmoidf_(fmaf(x, wiz, bz_) + az);
        float nn = tanhf_(fmaf(x, win, bn_) + r*(an + bhn_));
        hm = (1.f - z)*nn + z*hm;
        hnxt[chp] = (_Float16)hm;
      }
      __syncthreads();
    }
    if (kq == 0){
      const int off = isF ? d*128 : 256 + d*128;
      feats[(size_t)i*512 + off + p] = hm;
    }
    __syncthreads();
  }
}

// ---------------- classifier ----------------
__global__ __launch_bounds__(256) void k_cls(const float* __restrict__ feats,
    const float* __restrict__ w1, const float* __restrict__ b1,
    const float* __restrict__ w2, const float* __restrict__ b2,
    const float* __restrict__ w3, const float* __restrict__ b3,
    float* __restrict__ out){
  const int n = blockIdx.x; const int tid = threadIdx.x;
  __shared__ float fr[512];
  __shared__ float h1s[256];
  __shared__ float h2s[128];
  fr[tid]       = feats[(size_t)n*512 + tid];
  fr[tid+256]   = feats[(size_t)n*512 + 256 + tid];
  __syncthreads();
  {
    const float4* w  = (const float4*)(w1 + (size_t)tid*512);
    const float4* fp = (const float4*)fr;
    float a0=0,a1=0,a2=0,a3=0;
    #pragma unroll 8
    for (int q=0;q<128;q++){ float4 wv=w[q], fv=fp[q];
      a0=fmaf(wv.x,fv.x,a0); a1=fmaf(wv.y,fv.y,a1); a2=fmaf(wv.z,fv.z,a2); a3=fmaf(wv.w,fv.w,a3); }
    h1s[tid] = lrelu_(b1[tid] + (a0+a1)+(a2+a3));
  }
  __syncthreads();
  if (tid < 128){
    const float4* w  = (const float4*)(w2 + (size_t)tid*256);
    const float4* fp = (const float4*)h1s;
    float a0=0,a1=0,a2=0,a3=0;
    #pragma unroll 8
    for (int q=0;q<64;q++){ float4 wv=w[q], fv=fp[q];
      a0=fmaf(wv.x,fv.x,a0); a1=fmaf(wv.y,fv.y,a1); a2=fmaf(wv.z,fv.z,a2); a3=fmaf(wv.w,fv.w,a3); }
    h2s[tid] = lrelu_(b2[tid] + (a0+a1)+(a2+a3));
  }
  __syncthreads();
  if (tid < NCLS){
    const float4* w  = (const float4*)(w3 + (size_t)tid*128);
    const float4* fp = (const float4*)h2s;
    float a0=0,a1=0,a2=0,a3=0;
    #pragma unroll 8
    for (int q=0;q<32;q++){ float4 wv=w[q], fv=fp[q];
      a0=fmaf(wv.x,fv.x,a0); a1=fmaf(wv.y,fv.y,a1); a2=fmaf(wv.z,fv.z,a2); a3=fmaf(wv.w,fv.w,a3); }
    out[(size_t)n*NCLS + tid] = b3[tid] + (a0+a1)+(a2+a3);
  }
}

// ---------------- workspace layout (bytes) ----------------
#define OFF_FLAGS  0u
#define OFF_SALL   512u
#define OFF_AALL   2048u
#define OFF_ONED   133632u
#define OFF_HALL   395776u
#define OFF_FEATS  657920u
#define OFF_CNN    1182208u
#define OFF_POOL1  1894912u

extern "C" void kernel_launch(void* const* d_in, const int* in_sizes, int n_in,
                              void* d_out, int out_size, void* d_ws, size_t ws_size,
                              hipStream_t stream){
  const float* te   = (const float*)d_in[0];
  const float* tce  = (const float*)d_in[1];
  const float* c1w  = (const float*)d_in[2];
  const float* c1b  = (const float*)d_in[3];
  const float* c2w  = (const float*)d_in[4];
  const float* c2b  = (const float*)d_in[5];
  const float* uwif = (const float*)d_in[6];
  const float* uwhf = (const float*)d_in[7];
  const float* ubif = (const float*)d_in[8];
  const float* ubhf = (const float*)d_in[9];
  const float* uwib = (const float*)d_in[10];
  const float* uwhb = (const float*)d_in[11];
  const float* ubib = (const float*)d_in[12];
  const float* ubhb = (const float*)d_in[13];
  const float* cw1  = (const float*)d_in[14];
  const float* cw2  = (const float*)d_in[15];
  const float* cb2  = (const float*)d_in[16];
  const float* cw3  = (const float*)d_in[17];
  const float* pw   = (const float*)d_in[18];
  const float* pbb  = (const float*)d_in[19];
  const float* gx0  = (const float*)d_in[20];
  const float* gwif = (const float*)d_in[21];
  const float* gwhf = (const float*)d_in[22];
  const float* gbif = (const float*)d_in[23];
  const float* gbhf = (const float*)d_in[24];
  const float* gwib = (const float*)d_in[25];
  const float* gwhb = (const float*)d_in[26];
  const float* gbib = (const float*)d_in[27];
  const float* gbhb = (const float*)d_in[28];
  const float* clw1 = (const float*)d_in[29];
  const float* clb1 = (const float*)d_in[30];
  const float* clw2 = (const float*)d_in[31];
  const float* clb2 = (const float*)d_in[32];
  const float* clw3 = (const float*)d_in[33];
  const float* clb3 = (const float*)d_in[34];
  float* out = (float*)d_out;
  char* ws = (char*)d_ws;
  int*   flags = (int*)  (ws + OFF_FLAGS);
  float* s_all = (float*)(ws + OFF_SALL);
  float* a_all = (float*)(ws + OFF_AALL);
  float* one_d = (float*)(ws + OFF_ONED);
  float* Hall  = (float*)(ws + OFF_HALL);
  float* feats = (float*)(ws + OFF_FEATS);
  float* cnn   = (float*)(ws + OFF_CNN);
  float* pool1 = (float*)(ws + OFF_POOL1);

  hipMemsetAsync(flags, 0, 64, stream);
  k_conv1<<<dim3(TDIM, NB), 256, 0, stream>>>(tce, c1w, c1b, pool1);
  k_conv2<<<dim3(TDIM, NB), 128, 0, stream>>>(pool1, c2w, c2b, cnn);
  k_utt<<<512, 768, 0, stream>>>(te, cnn, uwif, uwhf, ubif, ubhf,
                                 uwib, uwhb, ubib, ubhb, Hall);
  k_prep<<<NB, 256, 0, stream>>>(Hall, cw1, pw, a_all, s_all);
  k_ctx<<<4, 512, 0, stream>>>(gwif, gwhf, gbif, gbhf, gwib, gwhb, gbib, gbhb,
                               cw2, cb2, cw3, pbb, gx0, a_all, s_all,
                               one_d, flags, feats);
  k_cls<<<NB, 256, 0, stream>>>(feats, clw1, clb1, clw2, clb2, clw3, clb3, out);
}